// Round 7
// baseline (649.767 us; speedup 1.0000x reference)
//
#include <hip/hip_runtime.h>
#include <math.h>

#define NNODES 200000
#define NG 1000
#define NPG 200
#define KNN 5
#define MD 128
#define S6 (1.0f / 6.0f)
#define NPAD 208  // 13 M-tiles of 16

typedef short short8 __attribute__((ext_vector_type(8)));
typedef float floatx4 __attribute__((ext_vector_type(4)));

// RNE bf16 split-pack: returns (bf16(v) << 16) | bf16(v - bf16(v))
__device__ __forceinline__ unsigned splitpack(float f) {
  unsigned u = __float_as_uint(f);
  unsigned hb = (u + 0x7fffu + ((u >> 16) & 1u)) >> 16;
  float hf = __uint_as_float(hb << 16);
  float r = f - hf;
  unsigned v = __float_as_uint(r);
  unsigned lb = (v + 0x7fffu + ((v >> 16) & 1u)) >> 16;
  return (hb << 16) | (lb & 0xffffu);
}

// reconstruct fp32 from packed split word: hi + lo
__device__ __forceinline__ float upk(unsigned w) {
  return __uint_as_float(w & 0xffff0000u) + __uint_as_float(w << 16);
}

__device__ __forceinline__ void unpack8(int4 u, int4 v, short8* hi, short8* lo) {
  unsigned w[8] = {(unsigned)u.x, (unsigned)u.y, (unsigned)u.z, (unsigned)u.w,
                   (unsigned)v.x, (unsigned)v.y, (unsigned)v.z, (unsigned)v.w};
  short8 h, l;
#pragma unroll
  for (int i = 0; i < 8; i++) {
    h[i] = (short)(w[i] >> 16);
    l[i] = (short)(w[i] & 0xffffu);
  }
  *hi = h;
  *lo = l;
}

// ---------------- kNN: one block per graph (validated R1..R5) ----------------
__global__ __launch_bounds__(256) void knn_kernel(const float* __restrict__ pos,
                                                  int* __restrict__ knn) {
  __shared__ float sp[NPG * 3];
  int g = blockIdx.x;
  int t = threadIdx.x;
  for (int i = t; i < NPG * 3; i += 256) sp[i] = pos[(size_t)g * NPG * 3 + i];
  __syncthreads();
  if (t < NPG) {
    float x = sp[t * 3 + 0], y = sp[t * 3 + 1], z = sp[t * 3 + 2];
    float bd[KNN];
    int bi[KNN];
#pragma unroll
    for (int k = 0; k < KNN; k++) { bd[k] = 3.0e38f; bi[k] = 0; }
    for (int j = 0; j < NPG; j++) {
      if (j == t) continue;
      float dx = __fsub_rn(x, sp[j * 3 + 0]);
      float dy = __fsub_rn(y, sp[j * 3 + 1]);
      float dz = __fsub_rn(z, sp[j * 3 + 2]);
      float d2 = __fadd_rn(__fadd_rn(__fmul_rn(dx, dx), __fmul_rn(dy, dy)),
                           __fmul_rn(dz, dz));
      if (d2 < bd[KNN - 1]) {
        bd[KNN - 1] = d2; bi[KNN - 1] = j;
#pragma unroll
        for (int k = KNN - 1; k > 0; k--) {
          if (bd[k] < bd[k - 1]) {
            float td = bd[k]; bd[k] = bd[k - 1]; bd[k - 1] = td;
            int ti = bi[k]; bi[k] = bi[k - 1]; bi[k - 1] = ti;
          }
        }
      }
    }
#pragma unroll
    for (int k = 0; k < KNN; k++)
      knn[((size_t)g * NPG + t) * KNN + k] = g * NPG + bi[k];
  }
}

// ---------------- embW0 = emb @ W0 (100x128 @ 128x128) ----------------
__global__ __launch_bounds__(256) void emb_gemm_kernel(const float* __restrict__ emb,
                                                       const float* __restrict__ W,
                                                       float* __restrict__ embW) {
  int idx = blockIdx.x * 256 + threadIdx.x;  // 12800 total
  int r = idx >> 7, c = idx & 127;
  float a = 0.0f;
  for (int k = 0; k < MD; k++) a += emb[r * MD + k] * W[k * MD + c];
  embW[idx] = a;
}

// ---------------- pre-pack W1,W2 into MFMA B-fragment layout (validated R5) ----
// [layer(2)][T(8)][c(4)][lane(64)][j(8)]: lane holds B[k=32c+8q+j][n=16T+m].
__global__ __launch_bounds__(256) void prepack_kernel(const float* __restrict__ convW,
                                                      unsigned short* __restrict__ WhiF,
                                                      unsigned short* __restrict__ WloF) {
  int idx = blockIdx.x * 256 + threadIdx.x;  // 0..4095
  int lane = idx & 63;
  int c = (idx >> 6) & 3;
  int T = (idx >> 8) & 7;
  int l = idx >> 11;  // 0..1 -> W1, W2
  const float* W = convW + (size_t)(l + 1) * MD * MD;
  int m = lane & 15, q = lane >> 4;
  int n = 16 * T + m;
  unsigned short hi[8], lo[8];
#pragma unroll
  for (int j = 0; j < 8; j++) {
    int k = 32 * c + 8 * q + j;
    unsigned p = splitpack(W[(size_t)k * MD + n]);
    hi[j] = (unsigned short)(p >> 16);
    lo[j] = (unsigned short)(p & 0xffffu);
  }
  *(short8*)(WhiF + (size_t)idx * 8) = *(short8*)hi;
  *(short8*)(WloF + (size_t)idx * 8) = *(short8*)lo;
}

// ---------------- mega: whole network per graph, x resident in LDS -----------
// 512 thr (8 waves, 2/SIMD -> 256 VGPR budget). Wave wv: mg=wv>>1 (M-tiles
// mg+4u, u<4), nh=wv&1 (col half). GEMM is c-outer/t-inner so A lives 8 regs;
// B-frags (128 regs) loaded once per layer; Cacc 64 regs. Peak ~230 VGPR.
__global__ __launch_bounds__(512, 2) void mega_kernel(
    const int* __restrict__ z, const int* __restrict__ knn,
    const float* __restrict__ embW, const float* __restrict__ convb,
    const unsigned short* __restrict__ WhiF, const unsigned short* __restrict__ WloF,
    const float* __restrict__ rW1, const float* __restrict__ rb1,
    const float* __restrict__ rW2, const float* __restrict__ rb2,
    const float* __restrict__ rW3, const float* __restrict__ rb3,
    float* __restrict__ out) {
  __shared__ unsigned Ax[NPAD * 128];  // 106,496 B
  __shared__ int kl[NPG * KNN];        // 4,000 B
  __shared__ int zi[NPG * 6];          // 4,800 B
  __shared__ float red[4 * 128];       // 2,048 B
  __shared__ float pooled[128];
  __shared__ float h1s[64];
  __shared__ float h2s[32];

  const int g = blockIdx.x;
  const int tid = threadIdx.x;

  // ---- phase 0: stage knn + z codes ----
  if (tid < 250) ((int4*)kl)[tid] = ((const int4*)(knn + (size_t)g * NPG * KNN))[tid];
  __syncthreads();
  for (int idx = tid; idx < NPG * 6; idx += 512) {
    int n = idx / 6, s = idx - 6 * n;
    int node = (s == 0) ? (g * NPG + n) : kl[n * KNN + (s - 1)];
    zi[idx] = z[node];
  }
  __syncthreads();

  // ---- phase 1: x1 = relu(s6*(sum embW rows) + b0), packed into Ax ----
  {
    const float4* G4 = (const float4*)embW;
    const float4* B40 = (const float4*)convb;
#pragma unroll
    for (int it = 0; it < 13; it++) {
      int idx = tid + 512 * it;
      if (idx < NPAD * 32) {
        int n = idx >> 5, kq = idx & 31;
        int4 pk = make_int4(0, 0, 0, 0);
        if (n < NPG) {
          const int* zz = zi + n * 6;
          float4 s = G4[(size_t)zz[0] * 32 + kq];
          float4 t1 = G4[(size_t)zz[1] * 32 + kq]; s.x += t1.x; s.y += t1.y; s.z += t1.z; s.w += t1.w;
          float4 t2 = G4[(size_t)zz[2] * 32 + kq]; s.x += t2.x; s.y += t2.y; s.z += t2.z; s.w += t2.w;
          float4 t3 = G4[(size_t)zz[3] * 32 + kq]; s.x += t3.x; s.y += t3.y; s.z += t3.z; s.w += t3.w;
          float4 t4 = G4[(size_t)zz[4] * 32 + kq]; s.x += t4.x; s.y += t4.y; s.z += t4.z; s.w += t4.w;
          float4 t5 = G4[(size_t)zz[5] * 32 + kq]; s.x += t5.x; s.y += t5.y; s.z += t5.z; s.w += t5.w;
          float4 bb = B40[kq];
          pk.x = (int)splitpack(fmaxf(s.x * S6 + bb.x, 0.0f));
          pk.y = (int)splitpack(fmaxf(s.y * S6 + bb.y, 0.0f));
          pk.z = (int)splitpack(fmaxf(s.z * S6 + bb.z, 0.0f));
          pk.w = (int)splitpack(fmaxf(s.w * S6 + bb.w, 0.0f));
        }
        *(int4*)(Ax + n * 128 + ((kq ^ (n & 7)) << 2)) = pk;
      }
    }
  }
  __syncthreads();

  const int lane = tid & 63;
  const int wv = tid >> 6;  // 0..7
  const int m = lane & 15;
  const int q = lane >> 4;
  const int mg = wv >> 1;   // 0..3: M-tiles mg+4u
  const int nh = wv & 1;    // col half

  // ---- phase 2: two GCN layers fully in LDS ----
  for (int l = 0; l < 2; l++) {
    // B fragments: once per layer, live through GEMM only (128 VGPRs)
    short8 bhi[4][4], blo[4][4];
    {
      const unsigned short* Whi = WhiF + (size_t)l * 16384;
      const unsigned short* Wlo = WloF + (size_t)l * 16384;
#pragma unroll
      for (int t = 0; t < 4; t++)
#pragma unroll
        for (int c = 0; c < 4; c++) {
          size_t off = ((size_t)((nh * 4 + t) * 4 + c) * 64 + lane) * 8;
          bhi[t][c] = *(const short8*)(Whi + off);
          blo[t][c] = *(const short8*)(Wlo + off);
        }
    }
    // GEMM: c-outer (A 8 regs), t-inner; Cacc[4][4] = 64 regs
    floatx4 Cacc[4][4];
#pragma unroll
    for (int u = 0; u < 4; u++) {
      int mt = mg + 4 * u;
      if (mt < 13) {
#pragma unroll
        for (int t = 0; t < 4; t++) Cacc[u][t] = (floatx4){0.f, 0.f, 0.f, 0.f};
        int r = mt * 16 + m;
        const unsigned* base = Ax + r * 128;
        int sw = r & 7;
#pragma unroll
        for (int c = 0; c < 4; c++) {
          int g1 = (8 * c + 2 * q) ^ sw;
          int g2 = (8 * c + 2 * q + 1) ^ sw;
          int4 uu = *(const int4*)(base + (g1 << 2));
          int4 vv = *(const int4*)(base + (g2 << 2));
          short8 ahi, alo;
          unpack8(uu, vv, &ahi, &alo);
#pragma unroll
          for (int t = 0; t < 4; t++) {
            Cacc[u][t] = __builtin_amdgcn_mfma_f32_16x16x32_bf16(ahi, bhi[t][c], Cacc[u][t], 0, 0, 0);
            Cacc[u][t] = __builtin_amdgcn_mfma_f32_16x16x32_bf16(ahi, blo[t][c], Cacc[u][t], 0, 0, 0);
            Cacc[u][t] = __builtin_amdgcn_mfma_f32_16x16x32_bf16(alo, bhi[t][c], Cacc[u][t], 0, 0, 0);
          }
        }
      }
    }
    __syncthreads();  // all x_l reads done
    // write h packed into Ax (C/D layout: col=16T+m, row=16mt+4q+reg)
#pragma unroll
    for (int u = 0; u < 4; u++) {
      int mt = mg + 4 * u;
      if (mt < 13) {
#pragma unroll
        for (int t = 0; t < 4; t++) {
          int col = nh * 64 + 16 * t + m;
          int colg = col >> 2, cw = col & 3;
#pragma unroll
          for (int reg = 0; reg < 4; reg++) {
            int row = mt * 16 + 4 * q + reg;
            if (row < NPG)
              Ax[row * 128 + ((colg ^ (row & 7)) << 2) + cw] = splitpack(Cacc[u][t][reg]);
          }
        }
      }
    }
    __syncthreads();
    // agg: x_{l+1} = relu(s6*(h self+5 nbrs) + b_{l+1}), staged in regs
    const float4* Bl = (const float4*)(convb + (size_t)(l + 1) * MD);
    int4 xa[13];
#pragma unroll
    for (int it = 0; it < 13; it++) {
      int idx = tid + 512 * it;
      if (idx < NPG * 32) {
        int n = idx >> 5, kq = idx & 31;
        const int* kn = kl + n * KNN;
        int rr[6];
        rr[0] = n;
        rr[1] = kn[0] - g * NPG; rr[2] = kn[1] - g * NPG; rr[3] = kn[2] - g * NPG;
        rr[4] = kn[3] - g * NPG; rr[5] = kn[4] - g * NPG;
        float4 s = make_float4(0.f, 0.f, 0.f, 0.f);
#pragma unroll
        for (int e = 0; e < 6; e++) {
          int r = rr[e];
          int4 w = *(const int4*)(Ax + r * 128 + ((kq ^ (r & 7)) << 2));
          s.x += upk((unsigned)w.x);
          s.y += upk((unsigned)w.y);
          s.z += upk((unsigned)w.z);
          s.w += upk((unsigned)w.w);
        }
        float4 bb = Bl[kq];
        int4 pk;
        pk.x = (int)splitpack(fmaxf(s.x * S6 + bb.x, 0.0f));
        pk.y = (int)splitpack(fmaxf(s.y * S6 + bb.y, 0.0f));
        pk.z = (int)splitpack(fmaxf(s.z * S6 + bb.z, 0.0f));
        pk.w = (int)splitpack(fmaxf(s.w * S6 + bb.w, 0.0f));
        xa[it] = pk;
      }
    }
    __syncthreads();  // all h reads done
#pragma unroll
    for (int it = 0; it < 13; it++) {
      int idx = tid + 512 * it;
      if (idx < NPG * 32) {
        int n = idx >> 5, kq = idx & 31;
        *(int4*)(Ax + n * 128 + ((kq ^ (n & 7)) << 2)) = xa[it];
      }
    }
    __syncthreads();
  }

  // ---- phase 3: mean pool + MLP ----
  {
    int col = tid & 127, grp = tid >> 7;  // 4 groups x 50 rows
    int colg = col >> 2, cw = col & 3;
    float s = 0.0f;
    for (int j = 0; j < 50; j++) {
      int n = grp * 50 + j;
      s += upk(Ax[n * 128 + ((colg ^ (n & 7)) << 2) + cw]);
    }
    red[grp * 128 + col] = s;
  }
  __syncthreads();
  if (tid < 128) {
    float p = 0.0f;
#pragma unroll
    for (int r = 0; r < 4; r++) p += red[r * 128 + tid];
    pooled[tid] = p / (float)NPG;
  }
  __syncthreads();
  if (tid < 64) {
    float a = rb1[tid];
    for (int c = 0; c < 128; c++) a += pooled[c] * rW1[c * 64 + tid];
    h1s[tid] = fmaxf(a, 0.0f);
  }
  __syncthreads();
  if (tid < 32) {
    float a = rb2[tid];
    for (int c = 0; c < 64; c++) a += h1s[c] * rW2[c * 32 + tid];
    h2s[tid] = fmaxf(a, 0.0f);
  }
  __syncthreads();
  if (tid == 0) {
    float a = rb3[0];
    for (int c = 0; c < 32; c++) a += h2s[c] * rW3[c];
    out[g] = a;
  }
}

extern "C" void kernel_launch(void* const* d_in, const int* in_sizes, int n_in,
                              void* d_out, int out_size, void* d_ws, size_t ws_size,
                              hipStream_t stream) {
  const int* z = (const int*)d_in[0];
  const float* pos = (const float*)d_in[1];
  const float* emb = (const float*)d_in[3];
  const float* convW = (const float*)d_in[4];  // [3][128][128]
  const float* convb = (const float*)d_in[5];  // [3][128]
  const float* rW1 = (const float*)d_in[6];
  const float* rb1 = (const float*)d_in[7];
  const float* rW2 = (const float*)d_in[8];
  const float* rb2 = (const float*)d_in[9];
  const float* rW3 = (const float*)d_in[10];
  const float* rb3 = (const float*)d_in[11];
  float* out = (float*)d_out;

  char* ws = (char*)d_ws;
  int* knn = (int*)ws;                                   // 4,000,000 B
  float* embW = (float*)(ws + 4000000);                  // 51,200 B
  unsigned short* WhiF = (unsigned short*)(ws + 4000000 + 51200);  // 65,536 B
  unsigned short* WloF = WhiF + 32768;                   // 65,536 B

  knn_kernel<<<NG, 256, 0, stream>>>(pos, knn);
  emb_gemm_kernel<<<50, 256, 0, stream>>>(emb, convW, embW);
  prepack_kernel<<<16, 256, 0, stream>>>(convW, WhiF, WloF);
  mega_kernel<<<NG, 512, 0, stream>>>(z, knn, embW, convb, WhiF, WloF, rW1,
                                      rb1, rW2, rb2, rW3, rb3, out);
}

// Round 8
// 600.205 us; speedup vs baseline: 1.0826x; 1.0826x over previous
//
#include <hip/hip_runtime.h>
#include <math.h>

#define NNODES 200000
#define NG 1000
#define NPG 200
#define KNN 5
#define MD 128
#define S6 (1.0f / 6.0f)
#define NPAD 208  // 13 M-tiles of 16

typedef short short8 __attribute__((ext_vector_type(8)));
typedef float floatx4 __attribute__((ext_vector_type(4)));

// RNE bf16 split-pack: returns (bf16(v) << 16) | bf16(v - bf16(v))
__device__ __forceinline__ unsigned splitpack(float f) {
  unsigned u = __float_as_uint(f);
  unsigned hb = (u + 0x7fffu + ((u >> 16) & 1u)) >> 16;
  float hf = __uint_as_float(hb << 16);
  float r = f - hf;
  unsigned v = __float_as_uint(r);
  unsigned lb = (v + 0x7fffu + ((v >> 16) & 1u)) >> 16;
  return (hb << 16) | (lb & 0xffffu);
}

// reconstruct fp32 from packed split word: hi + lo
__device__ __forceinline__ float upk(unsigned w) {
  return __uint_as_float(w & 0xffff0000u) + __uint_as_float(w << 16);
}

__device__ __forceinline__ void unpack8(int4 u, int4 v, short8* hi, short8* lo) {
  unsigned w[8] = {(unsigned)u.x, (unsigned)u.y, (unsigned)u.z, (unsigned)u.w,
                   (unsigned)v.x, (unsigned)v.y, (unsigned)v.z, (unsigned)v.w};
  short8 h, l;
#pragma unroll
  for (int i = 0; i < 8; i++) {
    h[i] = (short)(w[i] >> 16);
    l[i] = (short)(w[i] & 0xffffu);
  }
  *hi = h;
  *lo = l;
}

// ---------------- kNN: one block per graph (validated R1..R5) ----------------
__global__ __launch_bounds__(256) void knn_kernel(const float* __restrict__ pos,
                                                  int* __restrict__ knn) {
  __shared__ float sp[NPG * 3];
  int g = blockIdx.x;
  int t = threadIdx.x;
  for (int i = t; i < NPG * 3; i += 256) sp[i] = pos[(size_t)g * NPG * 3 + i];
  __syncthreads();
  if (t < NPG) {
    float x = sp[t * 3 + 0], y = sp[t * 3 + 1], z = sp[t * 3 + 2];
    float bd[KNN];
    int bi[KNN];
#pragma unroll
    for (int k = 0; k < KNN; k++) { bd[k] = 3.0e38f; bi[k] = 0; }
    for (int j = 0; j < NPG; j++) {
      if (j == t) continue;
      float dx = __fsub_rn(x, sp[j * 3 + 0]);
      float dy = __fsub_rn(y, sp[j * 3 + 1]);
      float dz = __fsub_rn(z, sp[j * 3 + 2]);
      float d2 = __fadd_rn(__fadd_rn(__fmul_rn(dx, dx), __fmul_rn(dy, dy)),
                           __fmul_rn(dz, dz));
      if (d2 < bd[KNN - 1]) {
        bd[KNN - 1] = d2; bi[KNN - 1] = j;
#pragma unroll
        for (int k = KNN - 1; k > 0; k--) {
          if (bd[k] < bd[k - 1]) {
            float td = bd[k]; bd[k] = bd[k - 1]; bd[k - 1] = td;
            int ti = bi[k]; bi[k] = bi[k - 1]; bi[k - 1] = ti;
          }
        }
      }
    }
#pragma unroll
    for (int k = 0; k < KNN; k++)
      knn[((size_t)g * NPG + t) * KNN + k] = g * NPG + bi[k];
  }
}

// ---------------- embW0 = emb @ W0 (100x128 @ 128x128) ----------------
__global__ __launch_bounds__(256) void emb_gemm_kernel(const float* __restrict__ emb,
                                                       const float* __restrict__ W,
                                                       float* __restrict__ embW) {
  int idx = blockIdx.x * 256 + threadIdx.x;  // 12800 total
  int r = idx >> 7, c = idx & 127;
  float a = 0.0f;
  for (int k = 0; k < MD; k++) a += emb[r * MD + k] * W[k * MD + c];
  embW[idx] = a;
}

// ---------------- pre-pack W1,W2 into MFMA B-fragment layout (validated R5) ----
// [layer(2)][T(8)][c(4)][lane(64)][j(8)]: lane holds B[k=32c+8q+j][n=16T+m].
__global__ __launch_bounds__(256) void prepack_kernel(const float* __restrict__ convW,
                                                      unsigned short* __restrict__ WhiF,
                                                      unsigned short* __restrict__ WloF) {
  int idx = blockIdx.x * 256 + threadIdx.x;  // 0..4095
  int lane = idx & 63;
  int c = (idx >> 6) & 3;
  int T = (idx >> 8) & 7;
  int l = idx >> 11;  // 0..1 -> W1, W2
  const float* W = convW + (size_t)(l + 1) * MD * MD;
  int m = lane & 15, q = lane >> 4;
  int n = 16 * T + m;
  unsigned short hi[8], lo[8];
#pragma unroll
  for (int j = 0; j < 8; j++) {
    int k = 32 * c + 8 * q + j;
    unsigned p = splitpack(W[(size_t)k * MD + n]);
    hi[j] = (unsigned short)(p >> 16);
    lo[j] = (unsigned short)(p & 0xffffu);
  }
  *(short8*)(WhiF + (size_t)idx * 8) = *(short8*)hi;
  *(short8*)(WloF + (size_t)idx * 8) = *(short8*)lo;
}

// ---------------- mega: whole network per graph, x resident in LDS -----------
// 512 thr (8 waves). Wave wv: mg=wv>>1 (M-tiles mg+4v, v<4), nh=wv&1 (col
// half). Register discipline (R5-validated): B-frags STREAMED from L2 per
// (t,c) (8 regs transient, never resident); A-frags resident for only 2
// M-tiles per pass (64 arch); Cacc[4][4] in accum half (64); h written once
// after both passes. Peak arch ~100, total ~165 -> no spill.
__global__ __launch_bounds__(512) void mega_kernel(
    const int* __restrict__ z, const int* __restrict__ knn,
    const float* __restrict__ embW, const float* __restrict__ convb,
    const unsigned short* __restrict__ WhiF, const unsigned short* __restrict__ WloF,
    const float* __restrict__ rW1, const float* __restrict__ rb1,
    const float* __restrict__ rW2, const float* __restrict__ rb2,
    const float* __restrict__ rW3, const float* __restrict__ rb3,
    float* __restrict__ out) {
  __shared__ unsigned Ax[NPAD * 128];  // 106,496 B
  __shared__ int kl[NPG * KNN];        // 4,000 B
  __shared__ int zi[NPG * 6];          // 4,800 B
  __shared__ float red[4 * 128];       // 2,048 B
  __shared__ float pooled[128];
  __shared__ float h1s[64];
  __shared__ float h2s[32];

  const int g = blockIdx.x;
  const int tid = threadIdx.x;

  // ---- phase 0: stage knn + z codes ----
  if (tid < 250) ((int4*)kl)[tid] = ((const int4*)(knn + (size_t)g * NPG * KNN))[tid];
  __syncthreads();
  for (int idx = tid; idx < NPG * 6; idx += 512) {
    int n = idx / 6, s = idx - 6 * n;
    int node = (s == 0) ? (g * NPG + n) : kl[n * KNN + (s - 1)];
    zi[idx] = z[node];
  }
  __syncthreads();

  // ---- phase 1: x1 = relu(s6*(sum embW rows) + b0), packed into Ax ----
  {
    const float4* G4 = (const float4*)embW;
    const float4* B40 = (const float4*)convb;
#pragma unroll
    for (int it = 0; it < 13; it++) {
      int idx = tid + 512 * it;
      if (idx < NPAD * 32) {
        int n = idx >> 5, kq = idx & 31;
        int4 pk = make_int4(0, 0, 0, 0);
        if (n < NPG) {
          const int* zz = zi + n * 6;
          float4 s = G4[(size_t)zz[0] * 32 + kq];
          float4 t1 = G4[(size_t)zz[1] * 32 + kq]; s.x += t1.x; s.y += t1.y; s.z += t1.z; s.w += t1.w;
          float4 t2 = G4[(size_t)zz[2] * 32 + kq]; s.x += t2.x; s.y += t2.y; s.z += t2.z; s.w += t2.w;
          float4 t3 = G4[(size_t)zz[3] * 32 + kq]; s.x += t3.x; s.y += t3.y; s.z += t3.z; s.w += t3.w;
          float4 t4 = G4[(size_t)zz[4] * 32 + kq]; s.x += t4.x; s.y += t4.y; s.z += t4.z; s.w += t4.w;
          float4 t5 = G4[(size_t)zz[5] * 32 + kq]; s.x += t5.x; s.y += t5.y; s.z += t5.z; s.w += t5.w;
          float4 bb = B40[kq];
          pk.x = (int)splitpack(fmaxf(s.x * S6 + bb.x, 0.0f));
          pk.y = (int)splitpack(fmaxf(s.y * S6 + bb.y, 0.0f));
          pk.z = (int)splitpack(fmaxf(s.z * S6 + bb.z, 0.0f));
          pk.w = (int)splitpack(fmaxf(s.w * S6 + bb.w, 0.0f));
        }
        *(int4*)(Ax + n * 128 + ((kq ^ (n & 7)) << 2)) = pk;
      }
    }
  }
  __syncthreads();

  const int lane = tid & 63;
  const int wv = tid >> 6;  // 0..7
  const int m = lane & 15;
  const int q = lane >> 4;
  const int mg = wv >> 1;   // 0..3: M-tiles mg+4v
  const int nh = wv & 1;    // col half

  // ---- phase 2: two GCN layers fully in LDS ----
  for (int l = 0; l < 2; l++) {
    const unsigned short* Whi = WhiF + (size_t)l * 16384;
    const unsigned short* Wlo = WloF + (size_t)l * 16384;
    floatx4 Cacc[4][4];  // [v][t], accum half
#pragma unroll
    for (int v = 0; v < 4; v++)
#pragma unroll
      for (int t = 0; t < 4; t++) Cacc[v][t] = (floatx4){0.f, 0.f, 0.f, 0.f};

#pragma unroll
    for (int p = 0; p < 2; p++) {
      // A-frags for this pass: mt = mg + 4*(2p+u), u<2  (64 arch regs)
      short8 ahi[2][4], alo[2][4];
#pragma unroll
      for (int u = 0; u < 2; u++) {
        int mt = mg + 4 * (2 * p + u);
        if (mt < 13) {
          int r = mt * 16 + m;
          const unsigned* base = Ax + r * 128;
          int sw = r & 7;
#pragma unroll
          for (int c = 0; c < 4; c++) {
            int g1 = (8 * c + 2 * q) ^ sw;
            int g2 = (8 * c + 2 * q + 1) ^ sw;
            int4 uu = *(const int4*)(base + (g1 << 2));
            int4 vv = *(const int4*)(base + (g2 << 2));
            unpack8(uu, vv, &ahi[u][c], &alo[u][c]);
          }
        }
      }
      // MFMA: stream B per (t,c) from L2, consume immediately (R5 pattern)
#pragma unroll
      for (int t = 0; t < 4; t++) {
#pragma unroll
        for (int c = 0; c < 4; c++) {
          size_t off = ((size_t)((nh * 4 + t) * 4 + c) * 64 + lane) * 8;
          short8 bh = *(const short8*)(Whi + off);
          short8 bl = *(const short8*)(Wlo + off);
#pragma unroll
          for (int u = 0; u < 2; u++) {
            int v = 2 * p + u;
            int mt = mg + 4 * v;
            if (mt < 13) {
              Cacc[v][t] = __builtin_amdgcn_mfma_f32_16x16x32_bf16(ahi[u][c], bh, Cacc[v][t], 0, 0, 0);
              Cacc[v][t] = __builtin_amdgcn_mfma_f32_16x16x32_bf16(ahi[u][c], bl, Cacc[v][t], 0, 0, 0);
              Cacc[v][t] = __builtin_amdgcn_mfma_f32_16x16x32_bf16(alo[u][c], bh, Cacc[v][t], 0, 0, 0);
            }
          }
        }
      }
    }
    __syncthreads();  // all x_l reads done
    // write h packed into Ax (C/D layout: col=16T+m, row=16mt+4q+reg)
#pragma unroll
    for (int v = 0; v < 4; v++) {
      int mt = mg + 4 * v;
      if (mt < 13) {
#pragma unroll
        for (int t = 0; t < 4; t++) {
          int col = nh * 64 + 16 * t + m;
          int colg = col >> 2, cw = col & 3;
#pragma unroll
          for (int reg = 0; reg < 4; reg++) {
            int row = mt * 16 + 4 * q + reg;
            if (row < NPG)
              Ax[row * 128 + ((colg ^ (row & 7)) << 2) + cw] = splitpack(Cacc[v][t][reg]);
          }
        }
      }
    }
    __syncthreads();
    // agg: x_{l+1} = relu(s6*(h self+5 nbrs) + b_{l+1}), staged in regs
    const float4* Bl = (const float4*)(convb + (size_t)(l + 1) * MD);
    int4 xa[13];
#pragma unroll
    for (int it = 0; it < 13; it++) {
      int idx = tid + 512 * it;
      if (idx < NPG * 32) {
        int n = idx >> 5, kq = idx & 31;
        const int* kn = kl + n * KNN;
        int rr[6];
        rr[0] = n;
        rr[1] = kn[0] - g * NPG; rr[2] = kn[1] - g * NPG; rr[3] = kn[2] - g * NPG;
        rr[4] = kn[3] - g * NPG; rr[5] = kn[4] - g * NPG;
        float4 s = make_float4(0.f, 0.f, 0.f, 0.f);
#pragma unroll
        for (int e = 0; e < 6; e++) {
          int r = rr[e];
          int4 w = *(const int4*)(Ax + r * 128 + ((kq ^ (r & 7)) << 2));
          s.x += upk((unsigned)w.x);
          s.y += upk((unsigned)w.y);
          s.z += upk((unsigned)w.z);
          s.w += upk((unsigned)w.w);
        }
        float4 bb = Bl[kq];
        int4 pk;
        pk.x = (int)splitpack(fmaxf(s.x * S6 + bb.x, 0.0f));
        pk.y = (int)splitpack(fmaxf(s.y * S6 + bb.y, 0.0f));
        pk.z = (int)splitpack(fmaxf(s.z * S6 + bb.z, 0.0f));
        pk.w = (int)splitpack(fmaxf(s.w * S6 + bb.w, 0.0f));
        xa[it] = pk;
      }
    }
    __syncthreads();  // all h reads done
#pragma unroll
    for (int it = 0; it < 13; it++) {
      int idx = tid + 512 * it;
      if (idx < NPG * 32) {
        int n = idx >> 5, kq = idx & 31;
        *(int4*)(Ax + n * 128 + ((kq ^ (n & 7)) << 2)) = xa[it];
      }
    }
    __syncthreads();
  }

  // ---- phase 3: mean pool + MLP ----
  {
    int col = tid & 127, grp = tid >> 7;  // 4 groups x 50 rows
    int colg = col >> 2, cw = col & 3;
    float s = 0.0f;
    for (int j = 0; j < 50; j++) {
      int n = grp * 50 + j;
      s += upk(Ax[n * 128 + ((colg ^ (n & 7)) << 2) + cw]);
    }
    red[grp * 128 + col] = s;
  }
  __syncthreads();
  if (tid < 128) {
    float p = 0.0f;
#pragma unroll
    for (int r = 0; r < 4; r++) p += red[r * 128 + tid];
    pooled[tid] = p / (float)NPG;
  }
  __syncthreads();
  if (tid < 64) {
    float a = rb1[tid];
    for (int c = 0; c < 128; c++) a += pooled[c] * rW1[c * 64 + tid];
    h1s[tid] = fmaxf(a, 0.0f);
  }
  __syncthreads();
  if (tid < 32) {
    float a = rb2[tid];
    for (int c = 0; c < 64; c++) a += h1s[c] * rW2[c * 32 + tid];
    h2s[tid] = fmaxf(a, 0.0f);
  }
  __syncthreads();
  if (tid == 0) {
    float a = rb3[0];
    for (int c = 0; c < 32; c++) a += h2s[c] * rW3[c];
    out[g] = a;
  }
}

extern "C" void kernel_launch(void* const* d_in, const int* in_sizes, int n_in,
                              void* d_out, int out_size, void* d_ws, size_t ws_size,
                              hipStream_t stream) {
  const int* z = (const int*)d_in[0];
  const float* pos = (const float*)d_in[1];
  const float* emb = (const float*)d_in[3];
  const float* convW = (const float*)d_in[4];  // [3][128][128]
  const float* convb = (const float*)d_in[5];  // [3][128]
  const float* rW1 = (const float*)d_in[6];
  const float* rb1 = (const float*)d_in[7];
  const float* rW2 = (const float*)d_in[8];
  const float* rb2 = (const float*)d_in[9];
  const float* rW3 = (const float*)d_in[10];
  const float* rb3 = (const float*)d_in[11];
  float* out = (float*)d_out;

  char* ws = (char*)d_ws;
  int* knn = (int*)ws;                                   // 4,000,000 B
  float* embW = (float*)(ws + 4000000);                  // 51,200 B
  unsigned short* WhiF = (unsigned short*)(ws + 4000000 + 51200);  // 65,536 B
  unsigned short* WloF = WhiF + 32768;                   // 65,536 B

  knn_kernel<<<NG, 256, 0, stream>>>(pos, knn);
  emb_gemm_kernel<<<50, 256, 0, stream>>>(emb, convW, embW);
  prepack_kernel<<<16, 256, 0, stream>>>(convW, WhiF, WloF);
  mega_kernel<<<NG, 512, 0, stream>>>(z, knn, embW, convb, WhiF, WloF, rW1,
                                      rb1, rW2, rb2, rW3, rb3, out);
}

// Round 9
// 386.027 us; speedup vs baseline: 1.6832x; 1.5548x over previous
//
#include <hip/hip_runtime.h>
#include <math.h>

#define NNODES 200000
#define NG 1000
#define NPG 200
#define KNN 5
#define MD 128
#define S6 (1.0f / 6.0f)

typedef short short8 __attribute__((ext_vector_type(8)));
typedef float floatx4 __attribute__((ext_vector_type(4)));

// RNE bf16 split-pack: returns (bf16(v) << 16) | bf16(v - bf16(v))
__device__ __forceinline__ unsigned splitpack(float f) {
  unsigned u = __float_as_uint(f);
  unsigned hb = (u + 0x7fffu + ((u >> 16) & 1u)) >> 16;
  float hf = __uint_as_float(hb << 16);
  float r = f - hf;
  unsigned v = __float_as_uint(r);
  unsigned lb = (v + 0x7fffu + ((v >> 16) & 1u)) >> 16;
  return (hb << 16) | (lb & 0xffffu);
}

// ---------------- kNN: one block per graph (validated R1..R5) ----------------
__global__ __launch_bounds__(256) void knn_kernel(const float* __restrict__ pos,
                                                  int* __restrict__ knn) {
  __shared__ float sp[NPG * 3];
  int g = blockIdx.x;
  int t = threadIdx.x;
  for (int i = t; i < NPG * 3; i += 256) sp[i] = pos[(size_t)g * NPG * 3 + i];
  __syncthreads();
  if (t < NPG) {
    float x = sp[t * 3 + 0], y = sp[t * 3 + 1], z = sp[t * 3 + 2];
    float bd[KNN];
    int bi[KNN];
#pragma unroll
    for (int k = 0; k < KNN; k++) { bd[k] = 3.0e38f; bi[k] = 0; }
    for (int j = 0; j < NPG; j++) {
      if (j == t) continue;
      float dx = __fsub_rn(x, sp[j * 3 + 0]);
      float dy = __fsub_rn(y, sp[j * 3 + 1]);
      float dz = __fsub_rn(z, sp[j * 3 + 2]);
      float d2 = __fadd_rn(__fadd_rn(__fmul_rn(dx, dx), __fmul_rn(dy, dy)),
                           __fmul_rn(dz, dz));
      if (d2 < bd[KNN - 1]) {
        bd[KNN - 1] = d2; bi[KNN - 1] = j;
#pragma unroll
        for (int k = KNN - 1; k > 0; k--) {
          if (bd[k] < bd[k - 1]) {
            float td = bd[k]; bd[k] = bd[k - 1]; bd[k - 1] = td;
            int ti = bi[k]; bi[k] = bi[k - 1]; bi[k - 1] = ti;
          }
        }
      }
    }
#pragma unroll
    for (int k = 0; k < KNN; k++)
      knn[((size_t)g * NPG + t) * KNN + k] = g * NPG + bi[k];
  }
}

// ---------------- embW0 = emb @ W0 (100x128 @ 128x128) ----------------
__global__ __launch_bounds__(256) void emb_gemm_kernel(const float* __restrict__ emb,
                                                       const float* __restrict__ W,
                                                       float* __restrict__ embW) {
  int idx = blockIdx.x * 256 + threadIdx.x;  // 12800 total
  int r = idx >> 7, c = idx & 127;
  float a = 0.0f;
  for (int k = 0; k < MD; k++) a += emb[r * MD + k] * W[k * MD + c];
  embW[idx] = a;
}

// ---------------- pre-pack W1,W2 into MFMA B-fragment layout (validated R5) ----
// [layer(2)][T(8)][c(4)][lane(64)][j(8)]: lane holds B[k=32c+8q+j][n=16T+m].
__global__ __launch_bounds__(256) void prepack_kernel(const float* __restrict__ convW,
                                                      unsigned short* __restrict__ WhiF,
                                                      unsigned short* __restrict__ WloF) {
  int idx = blockIdx.x * 256 + threadIdx.x;  // 0..4095
  int lane = idx & 63;
  int c = (idx >> 6) & 3;
  int T = (idx >> 8) & 7;
  int l = idx >> 11;  // 0..1 -> W1, W2
  const float* W = convW + (size_t)(l + 1) * MD * MD;
  int m = lane & 15, q = lane >> 4;
  int n = 16 * T + m;
  unsigned short hi[8], lo[8];
#pragma unroll
  for (int j = 0; j < 8; j++) {
    int k = 32 * c + 8 * q + j;
    unsigned p = splitpack(W[(size_t)k * MD + n]);
    hi[j] = (unsigned short)(p >> 16);
    lo[j] = (unsigned short)(p & 0xffffu);
  }
  *(short8*)(WhiF + (size_t)idx * 8) = *(short8*)hi;
  *(short8*)(WloF + (size_t)idx * 8) = *(short8*)lo;
}

// ---------------- fused agg + split-bf16 MFMA layer, NO LDS -----------------
// Block 256 thr (4 waves), no shared memory, no barriers. Wave wv owns M-tile
// rows [lb*64+16wv .. +16), all 128 cols. Lane (m,q) builds its own A-frag
// directly from global: A[m][k=8q+j+32c] = relu(s6*sum(6 src rows)+bias),
// split-packed in registers. B-frags streamed from prepacked L2-resident
// arrays per (t,c) (R5-validated). Cacc[8] = 32 accum regs.
template <int MODE>
__device__ __forceinline__ void layer_body(
    const int* __restrict__ z, const int* __restrict__ knn,
    const float* __restrict__ gsrc,  // MODE 0: embW[100][128]; MODE 1: h[N][128]
    const float* __restrict__ bias,  // this layer's bias (pre-relu) [128]
    const unsigned short* __restrict__ WhiF,
    const unsigned short* __restrict__ WloF,
    float* __restrict__ C) {
  const int tid = threadIdx.x;

  // XCD-aware remap (validated R5): 4 consecutive logical blocks per XCD.
  int b = blockIdx.x;
  int lb;
  if (b < 3072) {
    int grp = b >> 5, r8 = b & 7, r4 = (b >> 3) & 3;
    lb = grp * 32 + r8 * 4 + r4;
  } else {
    lb = b;
  }

  const int lane = tid & 63;
  const int wv = tid >> 6;
  const int m = lane & 15;
  const int q = lane >> 4;
  const int row = lb * 64 + wv * 16 + m;  // this lane's A-row

  // source row indices (same order as R5: self, then kn[0..4])
  const int* kn = knn + (size_t)row * KNN;
  int i0, i1, i2, i3, i4, i5;
  if (MODE == 0) {
    i0 = z[row];
    i1 = z[kn[0]]; i2 = z[kn[1]]; i3 = z[kn[2]]; i4 = z[kn[3]]; i5 = z[kn[4]];
  } else {
    i0 = row;
    i1 = kn[0]; i2 = kn[1]; i3 = kn[2]; i4 = kn[3]; i5 = kn[4];
  }

  const float4* G4 = (const float4*)gsrc;
  const float4* B4 = (const float4*)bias;

  // ---- build A fragments in registers: 4 k-chunks x float8 ----
  short8 ahi[4], alo[4];
#pragma unroll
  for (int c = 0; c < 4; c++) {
    int f4 = 8 * c + 2 * q;  // float4 index of k = 32c + 8q
    float4 sa = G4[(size_t)i0 * 32 + f4];
    float4 sb = G4[(size_t)i0 * 32 + f4 + 1];
    float4 ta, tb;
    ta = G4[(size_t)i1 * 32 + f4]; tb = G4[(size_t)i1 * 32 + f4 + 1];
    sa.x += ta.x; sa.y += ta.y; sa.z += ta.z; sa.w += ta.w;
    sb.x += tb.x; sb.y += tb.y; sb.z += tb.z; sb.w += tb.w;
    ta = G4[(size_t)i2 * 32 + f4]; tb = G4[(size_t)i2 * 32 + f4 + 1];
    sa.x += ta.x; sa.y += ta.y; sa.z += ta.z; sa.w += ta.w;
    sb.x += tb.x; sb.y += tb.y; sb.z += tb.z; sb.w += tb.w;
    ta = G4[(size_t)i3 * 32 + f4]; tb = G4[(size_t)i3 * 32 + f4 + 1];
    sa.x += ta.x; sa.y += ta.y; sa.z += ta.z; sa.w += ta.w;
    sb.x += tb.x; sb.y += tb.y; sb.z += tb.z; sb.w += tb.w;
    ta = G4[(size_t)i4 * 32 + f4]; tb = G4[(size_t)i4 * 32 + f4 + 1];
    sa.x += ta.x; sa.y += ta.y; sa.z += ta.z; sa.w += ta.w;
    sb.x += tb.x; sb.y += tb.y; sb.z += tb.z; sb.w += tb.w;
    ta = G4[(size_t)i5 * 32 + f4]; tb = G4[(size_t)i5 * 32 + f4 + 1];
    sa.x += ta.x; sa.y += ta.y; sa.z += ta.z; sa.w += ta.w;
    sb.x += tb.x; sb.y += tb.y; sb.z += tb.z; sb.w += tb.w;
    float4 bba = B4[f4], bbb = B4[f4 + 1];
    unsigned p0 = splitpack(fmaxf(sa.x * S6 + bba.x, 0.0f));
    unsigned p1 = splitpack(fmaxf(sa.y * S6 + bba.y, 0.0f));
    unsigned p2 = splitpack(fmaxf(sa.z * S6 + bba.z, 0.0f));
    unsigned p3 = splitpack(fmaxf(sa.w * S6 + bba.w, 0.0f));
    unsigned p4 = splitpack(fmaxf(sb.x * S6 + bbb.x, 0.0f));
    unsigned p5 = splitpack(fmaxf(sb.y * S6 + bbb.y, 0.0f));
    unsigned p6 = splitpack(fmaxf(sb.z * S6 + bbb.z, 0.0f));
    unsigned p7 = splitpack(fmaxf(sb.w * S6 + bbb.w, 0.0f));
    short8 h, l;
    h[0] = (short)(p0 >> 16); l[0] = (short)(p0 & 0xffffu);
    h[1] = (short)(p1 >> 16); l[1] = (short)(p1 & 0xffffu);
    h[2] = (short)(p2 >> 16); l[2] = (short)(p2 & 0xffffu);
    h[3] = (short)(p3 >> 16); l[3] = (short)(p3 & 0xffffu);
    h[4] = (short)(p4 >> 16); l[4] = (short)(p4 & 0xffffu);
    h[5] = (short)(p5 >> 16); l[5] = (short)(p5 & 0xffffu);
    h[6] = (short)(p6 >> 16); l[6] = (short)(p6 & 0xffffu);
    h[7] = (short)(p7 >> 16); l[7] = (short)(p7 & 0xffffu);
    ahi[c] = h; alo[c] = l;
  }

  // ---- MFMA: 8 N-tiles, B streamed per (t,c), consumed immediately ----
  floatx4 acc[8];
#pragma unroll
  for (int t = 0; t < 8; t++) acc[t] = (floatx4){0.f, 0.f, 0.f, 0.f};
#pragma unroll
  for (int t = 0; t < 8; t++) {
#pragma unroll
    for (int c = 0; c < 4; c++) {
      size_t off = ((size_t)(t * 4 + c) * 64 + lane) * 8;
      short8 bh = *(const short8*)(WhiF + off);
      short8 bl = *(const short8*)(WloF + off);
      acc[t] = __builtin_amdgcn_mfma_f32_16x16x32_bf16(ahi[c], bh, acc[t], 0, 0, 0);
      acc[t] = __builtin_amdgcn_mfma_f32_16x16x32_bf16(ahi[c], bl, acc[t], 0, 0, 0);
      acc[t] = __builtin_amdgcn_mfma_f32_16x16x32_bf16(alo[c], bh, acc[t], 0, 0, 0);
    }
  }

  // ---- store: C/D layout col = 16t+m, row = base + 4q + reg ----
  const int rbase = lb * 64 + wv * 16 + 4 * q;
#pragma unroll
  for (int t = 0; t < 8; t++) {
    int col = 16 * t + m;
#pragma unroll
    for (int reg = 0; reg < 4; reg++) {
      C[(size_t)(rbase + reg) * MD + col] = acc[t][reg];
    }
  }
}

__global__ __launch_bounds__(256) void layer1_kernel(
    const int* __restrict__ z, const int* __restrict__ knn,
    const float* __restrict__ embW, const float* __restrict__ b0,
    const unsigned short* __restrict__ WhiF, const unsigned short* __restrict__ WloF,
    float* __restrict__ C) {
  layer_body<0>(z, knn, embW, b0, WhiF, WloF, C);
}

__global__ __launch_bounds__(256) void layer2_kernel(
    const int* __restrict__ knn, const float* __restrict__ h,
    const float* __restrict__ b1,
    const unsigned short* __restrict__ WhiF, const unsigned short* __restrict__ WloF,
    float* __restrict__ C) {
  layer_body<1>(nullptr, knn, h, b1, WhiF, WloF, C);
}

// ---------------- tail: agg(layer3) + mean-pool + MLP, 512 thr/graph (R5) ----
__global__ __launch_bounds__(512) void tail_kernel(
    const float* __restrict__ h3, const int* __restrict__ knn,
    const float* __restrict__ b2, const float* __restrict__ rW1,
    const float* __restrict__ rb1, const float* __restrict__ rW2,
    const float* __restrict__ rb2, const float* __restrict__ rW3,
    const float* __restrict__ rb3, float* __restrict__ out) {
  __shared__ int kl[NPG * KNN];
  __shared__ float part[16 * MD];
  __shared__ float pooled[MD];
  __shared__ float h1s[64];
  __shared__ float h2s[32];
  int g = blockIdx.x;
  int t = threadIdx.x;
  if (t < 250) ((int4*)kl)[t] = ((const int4*)(knn + (size_t)g * NPG * KNN))[t];
  __syncthreads();

  const float4* H = (const float4*)h3;
  int group = t >> 5;  // 0..15
  int cq = t & 31;     // float4 column index
  float4 bb = ((const float4*)b2)[cq];
  float4 pool = make_float4(0.f, 0.f, 0.f, 0.f);
  for (int j = 0;; j++) {
    int n = group + 16 * j;
    if (n >= NPG) break;
    size_t gn = (size_t)g * NPG + n;
    const int* kn = kl + n * KNN;
    float4 s = H[gn * 32 + cq];
    int n0 = kn[0], n1 = kn[1], n2 = kn[2], n3 = kn[3], n4 = kn[4];
    float4 t1 = H[(size_t)n0 * 32 + cq]; s.x += t1.x; s.y += t1.y; s.z += t1.z; s.w += t1.w;
    float4 t2 = H[(size_t)n1 * 32 + cq]; s.x += t2.x; s.y += t2.y; s.z += t2.z; s.w += t2.w;
    float4 t3 = H[(size_t)n2 * 32 + cq]; s.x += t3.x; s.y += t3.y; s.z += t3.z; s.w += t3.w;
    float4 t4 = H[(size_t)n3 * 32 + cq]; s.x += t4.x; s.y += t4.y; s.z += t4.z; s.w += t4.w;
    float4 t5 = H[(size_t)n4 * 32 + cq]; s.x += t5.x; s.y += t5.y; s.z += t5.z; s.w += t5.w;
    pool.x += fmaxf(s.x * S6 + bb.x, 0.0f);
    pool.y += fmaxf(s.y * S6 + bb.y, 0.0f);
    pool.z += fmaxf(s.z * S6 + bb.z, 0.0f);
    pool.w += fmaxf(s.w * S6 + bb.w, 0.0f);
  }
  ((float4*)part)[group * 32 + cq] = pool;
  __syncthreads();
  if (t < 32) {
    float4 p = make_float4(0.f, 0.f, 0.f, 0.f);
    for (int gr = 0; gr < 16; gr++) {
      float4 qv = ((const float4*)part)[gr * 32 + t];
      p.x += qv.x; p.y += qv.y; p.z += qv.z; p.w += qv.w;
    }
    const float inv = 1.0f / (float)NPG;
    p.x *= inv; p.y *= inv; p.z *= inv; p.w *= inv;
    ((float4*)pooled)[t] = p;
  }
  __syncthreads();
  if (t < 64) {
    float a = rb1[t];
    for (int c = 0; c < 128; c++) a += pooled[c] * rW1[c * 64 + t];
    h1s[t] = fmaxf(a, 0.0f);
  }
  __syncthreads();
  if (t < 32) {
    float a = rb2[t];
    for (int c = 0; c < 64; c++) a += h1s[c] * rW2[c * 32 + t];
    h2s[t] = fmaxf(a, 0.0f);
  }
  __syncthreads();
  if (t == 0) {
    float a = rb3[0];
    for (int c = 0; c < 32; c++) a += h2s[c] * rW3[c];
    out[g] = a;
  }
}

extern "C" void kernel_launch(void* const* d_in, const int* in_sizes, int n_in,
                              void* d_out, int out_size, void* d_ws, size_t ws_size,
                              hipStream_t stream) {
  const int* z = (const int*)d_in[0];
  const float* pos = (const float*)d_in[1];
  const float* emb = (const float*)d_in[3];
  const float* convW = (const float*)d_in[4];  // [3][128][128]
  const float* convb = (const float*)d_in[5];  // [3][128]
  const float* rW1 = (const float*)d_in[6];
  const float* rb1 = (const float*)d_in[7];
  const float* rW2 = (const float*)d_in[8];
  const float* rb2 = (const float*)d_in[9];
  const float* rW3 = (const float*)d_in[10];
  const float* rb3 = (const float*)d_in[11];
  float* out = (float*)d_out;

  char* ws = (char*)d_ws;
  int* knn = (int*)ws;                                        // 4,000,000 B
  float* hA = (float*)(ws + 4000000);                         // 102,400,000 B (h2)
  float* hB = (float*)(ws + 4000000 + 102400000ULL);          // 102,400,000 B (h3)
  float* embW = (float*)(ws + 4000000 + 2 * 102400000ULL);    // 51,200 B
  unsigned short* WhiF = (unsigned short*)(ws + 4000000 + 2 * 102400000ULL + 51200);  // 65,536 B
  unsigned short* WloF = WhiF + 32768;                        // 65,536 B

  knn_kernel<<<NG, 256, 0, stream>>>(pos, knn);
  emb_gemm_kernel<<<50, 256, 0, stream>>>(emb, convW, embW);
  prepack_kernel<<<16, 256, 0, stream>>>(convW, WhiF, WloF);

  const int grid = NNODES / 64;  // 3125
  // h2 = relu(agg(embW[z]) + b0) @ W1
  layer1_kernel<<<grid, 256, 0, stream>>>(z, knn, embW, convb, WhiF, WloF, hA);
  // h3 = relu(agg(h2) + b1) @ W2
  layer2_kernel<<<grid, 256, 0, stream>>>(knn, hA, convb + MD, WhiF + 16384,
                                          WloF + 16384, hB);
  // layer-3 agg + mean-pool + MLP
  tail_kernel<<<NG, 512, 0, stream>>>(hB, knn, convb + 2 * MD, rW1, rb1, rW2,
                                      rb2, rW3, rb3, out);
}

// Round 10
// 297.430 us; speedup vs baseline: 2.1846x; 1.2979x over previous
//
#include <hip/hip_runtime.h>
#include <math.h>

#define NNODES 200000
#define NG 1000
#define NPG 200
#define KNN 5
#define MD 128
#define S6 (1.0f / 6.0f)
#define NPAD 208  // 13 M-tiles of 16

typedef short short8 __attribute__((ext_vector_type(8)));
typedef float floatx4 __attribute__((ext_vector_type(4)));

// RNE bf16 split-pack: returns (bf16(v) << 16) | bf16(v - bf16(v))
__device__ __forceinline__ unsigned splitpack(float f) {
  unsigned u = __float_as_uint(f);
  unsigned hb = (u + 0x7fffu + ((u >> 16) & 1u)) >> 16;
  float hf = __uint_as_float(hb << 16);
  float r = f - hf;
  unsigned v = __float_as_uint(r);
  unsigned lb = (v + 0x7fffu + ((v >> 16) & 1u)) >> 16;
  return (hb << 16) | (lb & 0xffffu);
}

// reconstruct fp32 from packed split word: hi + lo
__device__ __forceinline__ float upk(unsigned w) {
  return __uint_as_float(w & 0xffff0000u) + __uint_as_float(w << 16);
}

__device__ __forceinline__ void unpack8(int4 u, int4 v, short8* hi, short8* lo) {
  unsigned w[8] = {(unsigned)u.x, (unsigned)u.y, (unsigned)u.z, (unsigned)u.w,
                   (unsigned)v.x, (unsigned)v.y, (unsigned)v.z, (unsigned)v.w};
  short8 h, l;
#pragma unroll
  for (int i = 0; i < 8; i++) {
    h[i] = (short)(w[i] >> 16);
    l[i] = (short)(w[i] & 0xffffu);
  }
  *hi = h;
  *lo = l;
}

// ---------------- kNN: one block per graph (validated R1..R5) ----------------
__global__ __launch_bounds__(256) void knn_kernel(const float* __restrict__ pos,
                                                  int* __restrict__ knn) {
  __shared__ float sp[NPG * 3];
  int g = blockIdx.x;
  int t = threadIdx.x;
  for (int i = t; i < NPG * 3; i += 256) sp[i] = pos[(size_t)g * NPG * 3 + i];
  __syncthreads();
  if (t < NPG) {
    float x = sp[t * 3 + 0], y = sp[t * 3 + 1], z = sp[t * 3 + 2];
    float bd[KNN];
    int bi[KNN];
#pragma unroll
    for (int k = 0; k < KNN; k++) { bd[k] = 3.0e38f; bi[k] = 0; }
    for (int j = 0; j < NPG; j++) {
      if (j == t) continue;
      float dx = __fsub_rn(x, sp[j * 3 + 0]);
      float dy = __fsub_rn(y, sp[j * 3 + 1]);
      float dz = __fsub_rn(z, sp[j * 3 + 2]);
      float d2 = __fadd_rn(__fadd_rn(__fmul_rn(dx, dx), __fmul_rn(dy, dy)),
                           __fmul_rn(dz, dz));
      if (d2 < bd[KNN - 1]) {
        bd[KNN - 1] = d2; bi[KNN - 1] = j;
#pragma unroll
        for (int k = KNN - 1; k > 0; k--) {
          if (bd[k] < bd[k - 1]) {
            float td = bd[k]; bd[k] = bd[k - 1]; bd[k - 1] = td;
            int ti = bi[k]; bi[k] = bi[k - 1]; bi[k - 1] = ti;
          }
        }
      }
    }
#pragma unroll
    for (int k = 0; k < KNN; k++)
      knn[((size_t)g * NPG + t) * KNN + k] = g * NPG + bi[k];
  }
}

// ---------------- embW0 = emb @ W0 (100x128 @ 128x128) ----------------
__global__ __launch_bounds__(256) void emb_gemm_kernel(const float* __restrict__ emb,
                                                       const float* __restrict__ W,
                                                       float* __restrict__ embW) {
  int idx = blockIdx.x * 256 + threadIdx.x;  // 12800 total
  int r = idx >> 7, c = idx & 127;
  float a = 0.0f;
  for (int k = 0; k < MD; k++) a += emb[r * MD + k] * W[k * MD + c];
  embW[idx] = a;
}

// ---------------- pre-pack W1,W2 into MFMA B-fragment layout (validated R5) ----
// [layer(2)][T(8)][c(4)][lane(64)][j(8)]: lane holds B[k=32c+8q+j][n=16T+m].
__global__ __launch_bounds__(256) void prepack_kernel(const float* __restrict__ convW,
                                                      unsigned short* __restrict__ WhiF,
                                                      unsigned short* __restrict__ WloF) {
  int idx = blockIdx.x * 256 + threadIdx.x;  // 0..4095
  int lane = idx & 63;
  int c = (idx >> 6) & 3;
  int T = (idx >> 8) & 7;
  int l = idx >> 11;  // 0..1 -> W1, W2
  const float* W = convW + (size_t)(l + 1) * MD * MD;
  int m = lane & 15, q = lane >> 4;
  int n = 16 * T + m;
  unsigned short hi[8], lo[8];
#pragma unroll
  for (int j = 0; j < 8; j++) {
    int k = 32 * c + 8 * q + j;
    unsigned p = splitpack(W[(size_t)k * MD + n]);
    hi[j] = (unsigned short)(p >> 16);
    lo[j] = (unsigned short)(p & 0xffffu);
  }
  *(short8*)(WhiF + (size_t)idx * 8) = *(short8*)hi;
  *(short8*)(WloF + (size_t)idx * 8) = *(short8*)lo;
}

// ---------------- layer1: R5-validated fused agg + MFMA GEMM ----------------
// Block 256 thr (4 waves). BM=64 rows, BN=128. Wave wv: rh=wv&1 (row half),
// hf=wv>>1 (col half). As[64][128] packed, XOR-swizzled 4-word granules.
__global__ __launch_bounds__(256) void layer1_kernel(
    const int* __restrict__ z, const int* __restrict__ knn,
    const float* __restrict__ embW, const float* __restrict__ bias,
    const unsigned short* __restrict__ WhiF, const unsigned short* __restrict__ WloF,
    float* __restrict__ C) {
  __shared__ unsigned As[64 * 128];  // 32 KB
  const int tid = threadIdx.x;

  int b = blockIdx.x;
  int lb;
  if (b < 3072) {
    int grp = b >> 5, r8 = b & 7, r4 = (b >> 3) & 3;
    lb = grp * 32 + r8 * 4 + r4;
  } else {
    lb = b;
  }
  const int row0 = lb * 64;

  {
    int r = tid >> 2;
    int kq0 = tid & 3;
    int grow = row0 + r;
    const int* kn = knn + (size_t)grow * KNN;
    int i0 = z[grow];
    int i1 = z[kn[0]], i2 = z[kn[1]], i3 = z[kn[2]], i4 = z[kn[3]], i5 = z[kn[4]];
    const float4* G4 = (const float4*)embW;
    const float4* B4 = (const float4*)bias;
    int sw = r & 7;
#pragma unroll
    for (int p = 0; p < 8; p++) {
      int kq = kq0 + 4 * p;
      float4 s = G4[(size_t)i0 * 32 + kq];
      float4 t1 = G4[(size_t)i1 * 32 + kq]; s.x += t1.x; s.y += t1.y; s.z += t1.z; s.w += t1.w;
      float4 t2 = G4[(size_t)i2 * 32 + kq]; s.x += t2.x; s.y += t2.y; s.z += t2.z; s.w += t2.w;
      float4 t3 = G4[(size_t)i3 * 32 + kq]; s.x += t3.x; s.y += t3.y; s.z += t3.z; s.w += t3.w;
      float4 t4 = G4[(size_t)i4 * 32 + kq]; s.x += t4.x; s.y += t4.y; s.z += t4.z; s.w += t4.w;
      float4 t5 = G4[(size_t)i5 * 32 + kq]; s.x += t5.x; s.y += t5.y; s.z += t5.z; s.w += t5.w;
      float4 bb = B4[kq];
      int4 pk;
      pk.x = (int)splitpack(fmaxf(s.x * S6 + bb.x, 0.0f));
      pk.y = (int)splitpack(fmaxf(s.y * S6 + bb.y, 0.0f));
      pk.z = (int)splitpack(fmaxf(s.z * S6 + bb.z, 0.0f));
      pk.w = (int)splitpack(fmaxf(s.w * S6 + bb.w, 0.0f));
      *(int4*)(As + r * 128 + ((kq ^ sw) << 2)) = pk;
    }
  }
  __syncthreads();

  const int lane = tid & 63;
  const int wv = tid >> 6;
  const int m = lane & 15;
  const int q = lane >> 4;
  const int rh = wv & 1;
  const int hf = wv >> 1;

  short8 ahi[2][4], alo[2][4];
#pragma unroll
  for (int rt = 0; rt < 2; rt++) {
    int r = 32 * rh + 16 * rt + m;
    const unsigned* base = As + r * 128;
    int sw = m & 7;
#pragma unroll
    for (int c = 0; c < 4; c++) {
      int g1 = (2 * q + 8 * c) ^ sw;
      int g2 = (2 * q + 8 * c + 1) ^ sw;
      int4 u = *(const int4*)(base + (g1 << 2));
      int4 v = *(const int4*)(base + (g2 << 2));
      unpack8(u, v, &ahi[rt][c], &alo[rt][c]);
    }
  }

#pragma unroll
  for (int t = 0; t < 4; t++) {
    floatx4 acc[2];
    acc[0] = (floatx4){0.f, 0.f, 0.f, 0.f};
    acc[1] = (floatx4){0.f, 0.f, 0.f, 0.f};
    int T = hf * 4 + t;
#pragma unroll
    for (int c = 0; c < 4; c++) {
      size_t off = ((size_t)(T * 4 + c) * 64 + lane) * 8;
      short8 bhi = *(const short8*)(WhiF + off);
      short8 blo = *(const short8*)(WloF + off);
#pragma unroll
      for (int rt = 0; rt < 2; rt++) {
        acc[rt] = __builtin_amdgcn_mfma_f32_16x16x32_bf16(ahi[rt][c], bhi, acc[rt], 0, 0, 0);
        acc[rt] = __builtin_amdgcn_mfma_f32_16x16x32_bf16(ahi[rt][c], blo, acc[rt], 0, 0, 0);
        acc[rt] = __builtin_amdgcn_mfma_f32_16x16x32_bf16(alo[rt][c], bhi, acc[rt], 0, 0, 0);
      }
    }
    int col = 64 * hf + 16 * t + m;
#pragma unroll
    for (int rt = 0; rt < 2; rt++) {
#pragma unroll
      for (int reg = 0; reg < 4; reg++) {
        int row = row0 + 32 * rh + 16 * rt + 4 * q + reg;
        C[(size_t)row * MD + col] = acc[rt][reg];
      }
    }
  }
}

// ---------------- graph kernel: layer2 GEMM + agg3 + pool + MLP per graph ----
// 1 block = 1 graph, 512 thr (8 waves). Ax[208][128] packed split words,
// XOR-swizzled (R5 layout). Stage A2=relu(s6*agg(h2)+b1) -> GEMM vs W2
// (B streamed from L2, R5 pattern; Cacc[2][8] accum) -> write h3 packed back
// into Ax -> agg3+bias+relu+pool from LDS -> MLP -> out[g] (4 B).
__global__ __launch_bounds__(512) void graph_kernel(
    const float* __restrict__ h2, const int* __restrict__ knn,
    const float* __restrict__ b1, const float* __restrict__ b2,
    const unsigned short* __restrict__ WhiF, const unsigned short* __restrict__ WloF,
    const float* __restrict__ rW1, const float* __restrict__ rb1,
    const float* __restrict__ rW2, const float* __restrict__ rb2,
    const float* __restrict__ rW3, const float* __restrict__ rb3,
    float* __restrict__ out) {
  __shared__ unsigned Ax[NPAD * 128];  // 106,496 B
  __shared__ int kl[NPG * KNN];        // 4,000 B
  __shared__ float red[16 * 128];      // 8,192 B
  __shared__ float pooled[128];
  __shared__ float h1s[64];
  __shared__ float h2s[32];

  const int g = blockIdx.x;
  const int tid = threadIdx.x;

  // ---- phase 0: stage knn ----
  if (tid < 250) ((int4*)kl)[tid] = ((const int4*)(knn + (size_t)g * NPG * KNN))[tid];
  __syncthreads();

  // ---- phase 1: A2 = relu(s6*agg(h2) + b1), packed+swizzled into Ax ----
  {
    const float4* G4 = (const float4*)h2;
    const float4* B4 = (const float4*)b1;
#pragma unroll
    for (int it = 0; it < 13; it++) {
      int idx = tid + 512 * it;
      if (idx < NPG * 32) {
        int n = idx >> 5, kq = idx & 31;
        const int* kn = kl + n * KNN;
        size_t i0 = (size_t)g * NPG + n;
        float4 s = G4[i0 * 32 + kq];
        int n1 = kn[0], n2 = kn[1], n3 = kn[2], n4 = kn[3], n5 = kn[4];
        float4 t1 = G4[(size_t)n1 * 32 + kq]; s.x += t1.x; s.y += t1.y; s.z += t1.z; s.w += t1.w;
        float4 t2 = G4[(size_t)n2 * 32 + kq]; s.x += t2.x; s.y += t2.y; s.z += t2.z; s.w += t2.w;
        float4 t3 = G4[(size_t)n3 * 32 + kq]; s.x += t3.x; s.y += t3.y; s.z += t3.z; s.w += t3.w;
        float4 t4 = G4[(size_t)n4 * 32 + kq]; s.x += t4.x; s.y += t4.y; s.z += t4.z; s.w += t4.w;
        float4 t5 = G4[(size_t)n5 * 32 + kq]; s.x += t5.x; s.y += t5.y; s.z += t5.z; s.w += t5.w;
        float4 bb = B4[kq];
        int4 pk;
        pk.x = (int)splitpack(fmaxf(s.x * S6 + bb.x, 0.0f));
        pk.y = (int)splitpack(fmaxf(s.y * S6 + bb.y, 0.0f));
        pk.z = (int)splitpack(fmaxf(s.z * S6 + bb.z, 0.0f));
        pk.w = (int)splitpack(fmaxf(s.w * S6 + bb.w, 0.0f));
        *(int4*)(Ax + n * 128 + ((kq ^ (n & 7)) << 2)) = pk;
      }
    }
  }
  __syncthreads();

  const int lane = tid & 63;
  const int wv = tid >> 6;  // 0..7
  const int m = lane & 15;
  const int q = lane >> 4;

  // ---- phase 2: GEMM A2 @ W2. Wave wv -> M-tiles wv, wv+8. ----
  floatx4 Cacc[2][8];
#pragma unroll
  for (int u = 0; u < 2; u++) {
    int mt = wv + 8 * u;
    if (mt < 13) {
      // A-frags for this M-tile only (32 arch regs live)
      short8 ahi[4], alo[4];
      int r = mt * 16 + m;
      const unsigned* base = Ax + r * 128;
      int sw = r & 7;
#pragma unroll
      for (int c = 0; c < 4; c++) {
        int g1 = (2 * q + 8 * c) ^ sw;
        int g2 = (2 * q + 8 * c + 1) ^ sw;
        int4 uu = *(const int4*)(base + (g1 << 2));
        int4 vv = *(const int4*)(base + (g2 << 2));
        unpack8(uu, vv, &ahi[c], &alo[c]);
      }
#pragma unroll
      for (int t = 0; t < 8; t++) {
        floatx4 acc = (floatx4){0.f, 0.f, 0.f, 0.f};
#pragma unroll
        for (int c = 0; c < 4; c++) {
          size_t off = ((size_t)(t * 4 + c) * 64 + lane) * 8;
          short8 bh = *(const short8*)(WhiF + off);
          short8 bl = *(const short8*)(WloF + off);
          acc = __builtin_amdgcn_mfma_f32_16x16x32_bf16(ahi[c], bh, acc, 0, 0, 0);
          acc = __builtin_amdgcn_mfma_f32_16x16x32_bf16(ahi[c], bl, acc, 0, 0, 0);
          acc = __builtin_amdgcn_mfma_f32_16x16x32_bf16(alo[c], bh, acc, 0, 0, 0);
        }
        Cacc[u][t] = acc;
      }
    }
  }
  __syncthreads();  // all A2 reads done

  // ---- phase 3: write h3 packed into Ax (C/D: col=16t+m, row=16mt+4q+reg) ----
#pragma unroll
  for (int u = 0; u < 2; u++) {
    int mt = wv + 8 * u;
    if (mt < 13) {
#pragma unroll
      for (int t = 0; t < 8; t++) {
        int col = 16 * t + m;
        int colg = col >> 2, cw = col & 3;
#pragma unroll
        for (int reg = 0; reg < 4; reg++) {
          int row = mt * 16 + 4 * q + reg;
          if (row < NPG)
            Ax[row * 128 + ((colg ^ (row & 7)) << 2) + cw] = splitpack(Cacc[u][t][reg]);
        }
      }
    }
  }
  __syncthreads();

  // ---- phase 4: agg3 + bias + relu + pool (from LDS) ----
  {
    int kq = tid & 31;      // float4 col group
    int group = tid >> 5;   // 0..15
    float4 bb = ((const float4*)b2)[kq];
    float4 pool = make_float4(0.f, 0.f, 0.f, 0.f);
    for (int n = group; n < NPG; n += 16) {
      const int* kn = kl + n * KNN;
      int rr[6];
      rr[0] = n;
      rr[1] = kn[0] - g * NPG; rr[2] = kn[1] - g * NPG; rr[3] = kn[2] - g * NPG;
      rr[4] = kn[3] - g * NPG; rr[5] = kn[4] - g * NPG;
      float4 s = make_float4(0.f, 0.f, 0.f, 0.f);
#pragma unroll
      for (int e = 0; e < 6; e++) {
        int r = rr[e];
        int4 w = *(const int4*)(Ax + r * 128 + ((kq ^ (r & 7)) << 2));
        s.x += upk((unsigned)w.x);
        s.y += upk((unsigned)w.y);
        s.z += upk((unsigned)w.z);
        s.w += upk((unsigned)w.w);
      }
      pool.x += fmaxf(s.x * S6 + bb.x, 0.0f);
      pool.y += fmaxf(s.y * S6 + bb.y, 0.0f);
      pool.z += fmaxf(s.z * S6 + bb.z, 0.0f);
      pool.w += fmaxf(s.w * S6 + bb.w, 0.0f);
    }
    ((float4*)red)[group * 32 + kq] = pool;
  }
  __syncthreads();
  if (tid < 32) {
    float4 p = make_float4(0.f, 0.f, 0.f, 0.f);
#pragma unroll
    for (int gr = 0; gr < 16; gr++) {
      float4 qv = ((const float4*)red)[gr * 32 + tid];
      p.x += qv.x; p.y += qv.y; p.z += qv.z; p.w += qv.w;
    }
    const float inv = 1.0f / (float)NPG;
    p.x *= inv; p.y *= inv; p.z *= inv; p.w *= inv;
    ((float4*)pooled)[tid] = p;
  }
  __syncthreads();
  if (tid < 64) {
    float a = rb1[tid];
    for (int c = 0; c < 128; c++) a += pooled[c] * rW1[c * 64 + tid];
    h1s[tid] = fmaxf(a, 0.0f);
  }
  __syncthreads();
  if (tid < 32) {
    float a = rb2[tid];
    for (int c = 0; c < 64; c++) a += h1s[c] * rW2[c * 32 + tid];
    h2s[tid] = fmaxf(a, 0.0f);
  }
  __syncthreads();
  if (tid == 0) {
    float a = rb3[0];
    for (int c = 0; c < 32; c++) a += h2s[c] * rW3[c];
    out[g] = a;
  }
}

extern "C" void kernel_launch(void* const* d_in, const int* in_sizes, int n_in,
                              void* d_out, int out_size, void* d_ws, size_t ws_size,
                              hipStream_t stream) {
  const int* z = (const int*)d_in[0];
  const float* pos = (const float*)d_in[1];
  const float* emb = (const float*)d_in[3];
  const float* convW = (const float*)d_in[4];  // [3][128][128]
  const float* convb = (const float*)d_in[5];  // [3][128]
  const float* rW1 = (const float*)d_in[6];
  const float* rb1 = (const float*)d_in[7];
  const float* rW2 = (const float*)d_in[8];
  const float* rb2 = (const float*)d_in[9];
  const float* rW3 = (const float*)d_in[10];
  const float* rb3 = (const float*)d_in[11];
  float* out = (float*)d_out;

  char* ws = (char*)d_ws;
  int* knn = (int*)ws;                                        // 4,000,000 B
  float* hA = (float*)(ws + 4000000);                         // 102,400,000 B (h2)
  float* embW = (float*)(ws + 4000000 + 102400000ULL);        // 51,200 B
  unsigned short* WhiF = (unsigned short*)(ws + 4000000 + 102400000ULL + 51200);  // 65,536 B
  unsigned short* WloF = WhiF + 32768;                        // 65,536 B

  knn_kernel<<<NG, 256, 0, stream>>>(pos, knn);
  emb_gemm_kernel<<<50, 256, 0, stream>>>(emb, convW, embW);
  prepack_kernel<<<16, 256, 0, stream>>>(convW, WhiF, WloF);

  // h2 = relu(agg(embW[z]) + b0) @ W1   (R5-validated)
  layer1_kernel<<<NNODES / 64, 256, 0, stream>>>(z, knn, embW, convb, WhiF,
                                                 WloF, hA);
  // layer2 GEMM + agg3 + pool + MLP, one block per graph
  graph_kernel<<<NG, 512, 0, stream>>>(hA, knn, convb + MD, convb + 2 * MD,
                                       WhiF + 16384, WloF + 16384, rW1, rb1,
                                       rW2, rb2, rW3, rb3, out);
}